// Round 6
// baseline (183.873 us; speedup 1.0000x reference)
//
#include <hip/hip_runtime.h>

// AllPoleDigitalFilter via overlap-and-discard.
// R19 DIAGNOSTIC: x8 compute-repeat to (a) measure true per-wave compute
// time k via dur = overhead + 7k + k, and (b) force the lpc dispatch into
// the rocprof top-5 (fills are 41-44us; we never see our own counters).
// Three refuted theories (R15 TLP, R17 divergence, R18 I-cache) mean the
// dur=fill+kernel decomposition itself is suspect: data is equally
// consistent with kernel ~6us + ~70us harness overhead. This round
// distinguishes: dur ~120 => near-floor kernel; dur >=250 => real ~30us
// per-wave stall, and VALUBusy/Occupancy of the lpc dispatch tell us
// issue-bound vs latency-bound.
// Mechanics: opaque zero (v_mov asm) perturbs x/a base pointers per rep so
// the body is formally rep-dependent (no LICM hoist); asm volatile sinks
// on ring values keep non-storing reps live (rule #17); stores gated on
// rep==REPS-1 => output bit-identical to R18 (absmax 0.03515625).
// Body = R18 verbatim: rolled 6x5-group loop, coeff double-buffer,
// first-order K*x warm-start (warm 160/200), dual v2f rings, pk-FMA tree.

typedef float v2f __attribute__((ext_vector_type(2)));

#define BATCH 32
#define N_FRAMES 800
#define D_COEF 25
#define P_FRAME 80
#define T_SAMP 64000
#define LCH 40
#define CHUNKS 1600              // per batch row
#define REPS 8

// ring slot helpers (all args non-negative; +80 bias removes any doubt)
__device__ __forceinline__ constexpr int slotA(int s)  { return ((s + 80) % 40) / 2; }       // even s: wA[slotA].x=y[s]; odd s uses slotAy
__device__ __forceinline__ constexpr int slotAy(int s) { return ((s + 80 - 1) % 40) / 2; }   // odd s: wA[slotAy].y=y[s]
__device__ __forceinline__ constexpr int slotBx(int s) { return ((s + 80 - 1) % 40) / 2; }   // odd s: wB[slotBx].x=y[s]
__device__ __forceinline__ constexpr int slotBy(int s) { return ((s + 80 - 2) % 40) / 2; }   // even s: wB[slotBy].y=y[s]

__global__
__attribute__((amdgpu_flat_work_group_size(64, 64)))
__attribute__((amdgpu_waves_per_eu(1, 1)))
void lpc_kernel(const float* __restrict__ x,
                const float* __restrict__ a,
                float* __restrict__ out) {
    const int g = blockIdx.x * 64 + threadIdx.x;
    const int b = g / CHUNKS;
    const int ci = g - b * CHUNKS;
    const int s0 = ci * LCH;
    const int nb = (ci >= 4) ? ((ci - 4) >> 1) : 0;   // warm 160 (even ci) / 200 (odd ci); ci<4 exact from t=0
    const int t0 = nb * P_FRAME;

    const float* xrow0 = x + (size_t)b * T_SAMP;
    float* orow = out + (size_t)b * T_SAMP;
    const float* arow0 = a + (size_t)b * (N_FRAMES * D_COEF);

    const float inv_p = 1.0f / (float)P_FRAME;

    // Opaque zero: compiler cannot prove ==0, so rep-scaled pointer offsets
    // make each rep's computation formally distinct (prevents LICM/CSE
    // collapsing the repeat loop) while being numerically identity.
    int zero;
    asm volatile("v_mov_b32 %0, 0" : "=v"(zero));

#pragma unroll 1
    for (int rep = 0; rep < REPS; ++rep) {
        const float* xrow = xrow0 + zero * rep;
        const float* arow = arow0 + zero * rep;

        v2f wA[20], wB[20];
#pragma unroll
        for (int i = 0; i < 20; ++i) {
            wA[i].x = 0.0f; wA[i].y = 0.0f;
            wB[i].x = 0.0f; wB[i].y = 0.0f;
        }

        // Coefficient register double-buffer: ccur = frame nb, cnxt = nb+1.
        float ccur[D_COEF], cnxt[D_COEF], cfut[D_COEF];
        {
            const float* rc = arow + nb * D_COEF;
            const int n1i = (nb + 1 < N_FRAMES) ? nb + 1 : N_FRAMES - 1;
            const float* rn = arow + n1i * D_COEF;
#pragma unroll
            for (int q = 0; q < D_COEF; ++q) { ccur[q] = rc[q]; cnxt[q] = rn[q]; }
        }

        // First-order refined warm-start (validated R15/R16).
        if (nb > 0) {
            const float* rm1 = arow + (nb - 1) * D_COEF;
            const float gm1 = rm1[0];
            const float dg = (ccur[0] - gm1) * inv_p;

            float z[48];
#pragma unroll
            for (int q = 0; q < 12; ++q) {
                float4 xq = *(const float4*)(xrow + t0 - 48 + 4 * q);
                z[4 * q + 0] = xq.x; z[4 * q + 1] = xq.y;
                z[4 * q + 2] = xq.z; z[4 * q + 3] = xq.w;
            }
#pragma unroll
            for (int i = 0; i < 48; ++i) {
                float Kv = fmaf(dg, (float)(32 + i), gm1);
                z[i] *= Kv;
            }
            float am[24];
#pragma unroll
            for (int m = 0; m < 24; ++m) {
                float c0 = rm1[1 + m];
                am[m] = fmaf(ccur[1 + m] - c0, 0.7f, c0);
            }
#pragma unroll
            for (int i = 0; i < 24; ++i) {
                float s = z[24 + i];
#pragma unroll
                for (int m = 1; m <= 24; ++m) s = fmaf(-am[m - 1], z[24 + i - m], s);
                if (i & 1) { wA[slotAy(i)].y = s; wB[slotBx(i)].x = s; }
                else       { wA[slotA(i)].x  = s; wB[slotBy(i)].y = s; }
            }
        }

        float4 xc0 = *(const float4*)(xrow + t0);
        float4 xc1 = *(const float4*)(xrow + t0 + 4);
        float4 xn0 = *(const float4*)(xrow + t0 + 8);
        float4 xn1 = *(const float4*)(xrow + t0 + 12);

        float k = 0.0f, dk = 0.0f, nc1 = 0.0f, nc2 = 0.0f, dn1 = 0.0f, dn2 = 0.0f;
        v2f cp[11], d8[11];
#pragma unroll
        for (int r = 0; r < 11; ++r) { cp[r].x = 0.0f; cp[r].y = 0.0f; d8[r].x = 0.0f; d8[r].y = 0.0f; }

        // 6 iterations x 5 groups = 30 groups = 3 frames (ring pattern
        // period is exactly 5 groups; frames advance 0 mod 40).
#pragma unroll 1
        for (int it = 0; it < 6; ++it) {
            if ((it & 1) == 0) {
                float g0 = ccur[0];
                dk = (cnxt[0] - g0) * inv_p;
                k = g0;
                {
                    float c1 = ccur[1], c2 = ccur[2];
                    float d1 = (cnxt[1] - c1) * inv_p;
                    float d2 = (cnxt[2] - c2) * inv_p;
                    nc1 = -fmaf(d1, 3.5f, c1);  dn1 = -8.0f * d1;
                    nc2 = -fmaf(d2, 3.5f, c2);  dn2 = -8.0f * d2;
                }
#pragma unroll
                for (int r = 0; r < 11; ++r) {
                    float cLo = ccur[4 + 2 * r], cHi = ccur[3 + 2 * r];
                    float dLo = (cnxt[4 + 2 * r] - cLo) * inv_p;
                    float dHi = (cnxt[3 + 2 * r] - cHi) * inv_p;
                    cp[r].x = -fmaf(dLo, 3.5f, cLo);
                    cp[r].y = -fmaf(dHi, 3.5f, cHi);
                    d8[r].x = -8.0f * dLo;
                    d8[r].y = -8.0f * dHi;
                }
                if (it < 4) {
                    const int n2c = (nb + (it >> 1) + 2 < N_FRAMES) ? nb + (it >> 1) + 2 : N_FRAMES - 1;
                    const float* r2 = arow + n2c * D_COEF;
#pragma unroll
                    for (int q = 0; q < D_COEF; ++q) cfut[q] = r2[q];
                }
            }

#pragma unroll
            for (int gi = 0; gi < 5; ++gi) {
                const int tg = t0 + it * 40 + gi * 8;     // runtime (it), uniform shape
                int tp = tg + 16; if (tp > T_SAMP - 8) tp = T_SAMP - 8;
                float4 xf0 = *(const float4*)(xrow + tp);
                float4 xf1 = *(const float4*)(xrow + tp + 4);

#pragma unroll
                for (int j = 0; j < 8; ++j) {
                    const int P = 24 + gi * 8 + j;        // compile-time ring pos (mod-40)
                    float xv = (j == 0) ? xc0.x : (j == 1) ? xc0.y
                             : (j == 2) ? xc0.z : (j == 3) ? xc0.w
                             : (j == 4) ? xc1.x : (j == 5) ? xc1.y
                             : (j == 6) ? xc1.z : xc1.w;
                    float e = k * xv;

                    v2f A, B, C;
#pragma unroll
                    for (int r = 0; r < 11; ++r) {
                        v2f pr = (P & 1) ? wB[slotBx(P - 3 - 2 * r)]
                                         : wA[slotA(P - 4 - 2 * r)];
                        if (r == 0)          A = cp[r] * pr;
                        else if (r == 1)     B = cp[r] * pr;
                        else if (r == 2)     C = cp[r] * pr;
                        else if (r % 3 == 0) A += cp[r] * pr;
                        else if (r % 3 == 1) B += cp[r] * pr;
                        else                 C += cp[r] * pr;
                    }
                    v2f S = (A + B) + C;
                    float t1 = e + (S.x + S.y);
                    float ym1 = (P & 1) ? wA[slotA(P - 1)].x  : wA[slotAy(P - 1)].y;  // y[P-1]
                    float ym2 = (P & 1) ? wA[slotAy(P - 2)].y : wA[slotA(P - 2)].x;   // y[P-2]
                    float u = fmaf(nc2, ym2, t1);
                    float y = fmaf(nc1, ym1, u);

                    if (P & 1) {
                        wA[slotAy(P)].y = y;
                        wB[slotBx(P)].x = y;
                    } else {
                        wA[slotA(P)].x = y;
                        wB[slotBy(P)].y = y;
                    }
                    k += dk;
                }

                if (rep == REPS - 1 && (unsigned)(tg - s0) < 40u) {   // stores: last rep only
                    const int Q = 24 + gi * 8;            // even -> pairs from wA
                    *(float4*)(orow + tg)     = make_float4(wA[slotA(Q + 0)].x, wA[slotA(Q + 0)].y,
                                                            wA[slotA(Q + 2)].x, wA[slotA(Q + 2)].y);
                    *(float4*)(orow + tg + 4) = make_float4(wA[slotA(Q + 4)].x, wA[slotA(Q + 4)].y,
                                                            wA[slotA(Q + 6)].x, wA[slotA(Q + 6)].y);
                }

                nc1 += dn1; nc2 += dn2;
#pragma unroll
                for (int r = 0; r < 11; ++r) cp[r] += d8[r];   // v_pk_add_f32
                xc0 = xn0; xc1 = xn1;                     // rotate at group END
                xn0 = xf0; xn1 = xf1;
            }

            if ((it & 1) == 1 && it < 5) {
#pragma unroll
                for (int q = 0; q < D_COEF; ++q) { ccur[q] = cnxt[q]; cnxt[q] = cfut[q]; }
            }
        }

        // Keep non-storing reps live (rule #17): sink final ring state.
        asm volatile("" :: "v"(wA[7].x), "v"(wA[13].y), "v"(wB[3].x), "v"(wB[17].y));
    }
}

extern "C" void kernel_launch(void* const* d_in, const int* in_sizes, int n_in,
                              void* d_out, int out_size, void* d_ws, size_t ws_size,
                              hipStream_t stream) {
    const float* x = (const float*)d_in[0];
    const float* a = (const float*)d_in[1];
    float* out = (float*)d_out;

    dim3 block(64);
    dim3 grid(BATCH * CHUNKS / 64);      // 800 one-wave blocks
    hipLaunchKernelGGL(lpc_kernel, grid, block, 0, stream, x, a, out);
}

// Round 7
// 79.637 us; speedup vs baseline: 2.3089x; 2.3089x over previous
//
#include <hip/hip_runtime.h>

// AllPoleDigitalFilter via overlap-and-discard.
// R20: DEEP PREFETCH. R19 diagnostic (x8 repeat) resolved the budget:
// per-wave = ~40us = ~25us cold-memory latency (first touch, no TLP at
// 0.78 waves/SIMD) + ~15us warm compute (VALUBusy 50% vs 78% cap,
// hbm 1.2% => pure latency, zero BW pressure). Old x prefetch distance
// was 2 groups (~380 issue-cyc) << HBM ~900 cyc.
// Fix: the rolled 6x5-group loop admits distance-5 prefetch with ZERO
// rotation movs: per-gi slots xb0[5]/xb1[5], loaded at (it,gi), consumed
// at (it+1,gi) -- 5 groups (~1900 cyc) of latency hiding, all indices
// compile-time, and the old 8 movs/group pipeline rotation is deleted.
// Prologue front-loads coeff rows + warm-start z + first 5 group loads as
// independent in-flight loads. Consumed x values identical to R18 (same
// addresses, earlier issue) => bit-identical output (absmax 0.03515625).
// Body otherwise = R18: coeff double-buffer ccur/cnxt/cfut, first-order
// K*x warm-start (warm 160/200), dual v2f rings wA/wB, pk-FMA tree,
// per-8-group midpoint taps, LCH=40, 800 one-wave blocks, waves_per_eu(1,1).

typedef float v2f __attribute__((ext_vector_type(2)));

#define BATCH 32
#define N_FRAMES 800
#define D_COEF 25
#define P_FRAME 80
#define T_SAMP 64000
#define LCH 40
#define CHUNKS 1600              // per batch row

// ring slot helpers (all args non-negative; +80 bias removes any doubt)
__device__ __forceinline__ constexpr int slotA(int s)  { return ((s + 80) % 40) / 2; }       // even s: wA[slotA].x=y[s]; odd s uses slotAy
__device__ __forceinline__ constexpr int slotAy(int s) { return ((s + 80 - 1) % 40) / 2; }   // odd s: wA[slotAy].y=y[s]
__device__ __forceinline__ constexpr int slotBx(int s) { return ((s + 80 - 1) % 40) / 2; }   // odd s: wB[slotBx].x=y[s]
__device__ __forceinline__ constexpr int slotBy(int s) { return ((s + 80 - 2) % 40) / 2; }   // even s: wB[slotBy].y=y[s]

__global__
__attribute__((amdgpu_flat_work_group_size(64, 64)))
__attribute__((amdgpu_waves_per_eu(1, 1)))
void lpc_kernel(const float* __restrict__ x,
                const float* __restrict__ a,
                float* __restrict__ out) {
    const int g = blockIdx.x * 64 + threadIdx.x;
    const int b = g / CHUNKS;
    const int ci = g - b * CHUNKS;
    const int s0 = ci * LCH;
    const int nb = (ci >= 4) ? ((ci - 4) >> 1) : 0;   // warm 160 (even ci) / 200 (odd ci); ci<4 exact from t=0
    const int t0 = nb * P_FRAME;

    const float* xrow = x + (size_t)b * T_SAMP;
    float* orow = out + (size_t)b * T_SAMP;
    const float* arow = a + (size_t)b * (N_FRAMES * D_COEF);

    const float inv_p = 1.0f / (float)P_FRAME;

    v2f wA[20], wB[20];
#pragma unroll
    for (int i = 0; i < 20; ++i) {
        wA[i].x = 0.0f; wA[i].y = 0.0f;
        wB[i].x = 0.0f; wB[i].y = 0.0f;
    }

    // ---- front-loaded prologue: all independent loads in flight early ----

    // Coefficient register double-buffer: ccur = frame nb, cnxt = frame nb+1.
    float ccur[D_COEF], cnxt[D_COEF], cfut[D_COEF];
    {
        const float* rc = arow + nb * D_COEF;
        const int n1i = (nb + 1 < N_FRAMES) ? nb + 1 : N_FRAMES - 1;
        const float* rn = arow + n1i * D_COEF;
#pragma unroll
        for (int q = 0; q < D_COEF; ++q) { ccur[q] = rc[q]; cnxt[q] = rn[q]; }
    }

    // x prefetch slots: xb[gi] holds group gi of the CURRENT 5-group block.
    float4 xb0[5], xb1[5];
#pragma unroll
    for (int gi = 0; gi < 5; ++gi) {
        xb0[gi] = *(const float4*)(xrow + t0 + gi * 8);
        xb1[gi] = *(const float4*)(xrow + t0 + gi * 8 + 4);
    }

    // First-order refined warm-start (validated R15/R16): ring positions
    // P=0..23 hold y[t0-24 .. t0-1]. z window = x[t0-48 .. t0), sample
    // t0-48+i sits at p=32+i of frame nb-1; gain interpolated per sample;
    // taps interpolated at history midpoint (frac 0.7).
    if (nb > 0) {
        const float* rm1 = arow + (nb - 1) * D_COEF;
        const float gm1 = rm1[0];
        const float dg = (ccur[0] - gm1) * inv_p;

        float z[48];
#pragma unroll
        for (int q = 0; q < 12; ++q) {
            float4 xq = *(const float4*)(xrow + t0 - 48 + 4 * q);
            z[4 * q + 0] = xq.x; z[4 * q + 1] = xq.y;
            z[4 * q + 2] = xq.z; z[4 * q + 3] = xq.w;
        }
#pragma unroll
        for (int i = 0; i < 48; ++i) {
            float Kv = fmaf(dg, (float)(32 + i), gm1);
            z[i] *= Kv;
        }
        float am[24];
#pragma unroll
        for (int m = 0; m < 24; ++m) {
            float c0 = rm1[1 + m];
            am[m] = fmaf(ccur[1 + m] - c0, 0.7f, c0);
        }
#pragma unroll
        for (int i = 0; i < 24; ++i) {
            float s = z[24 + i];
#pragma unroll
            for (int m = 1; m <= 24; ++m) s = fmaf(-am[m - 1], z[24 + i - m], s);
            if (i & 1) { wA[slotAy(i)].y = s; wB[slotBx(i)].x = s; }
            else       { wA[slotA(i)].x  = s; wB[slotBy(i)].y = s; }
        }
    }

    float k = 0.0f, dk = 0.0f, nc1 = 0.0f, nc2 = 0.0f, dn1 = 0.0f, dn2 = 0.0f;
    v2f cp[11], d8[11];
#pragma unroll
    for (int r = 0; r < 11; ++r) { cp[r].x = 0.0f; cp[r].y = 0.0f; d8[r].x = 0.0f; d8[r].y = 0.0f; }

    // 6 iterations x 5 groups = 30 groups = 3 frames (ring pattern period
    // is exactly 5 groups; frames advance 0 mod 40).
#pragma unroll 1
    for (int it = 0; it < 6; ++it) {
        if ((it & 1) == 0) {
            // frame setup from resident registers (uniform branch)
            float g0 = ccur[0];
            dk = (cnxt[0] - g0) * inv_p;
            k = g0;
            {
                float c1 = ccur[1], c2 = ccur[2];
                float d1 = (cnxt[1] - c1) * inv_p;
                float d2 = (cnxt[2] - c2) * inv_p;
                nc1 = -fmaf(d1, 3.5f, c1);  dn1 = -8.0f * d1;
                nc2 = -fmaf(d2, 3.5f, c2);  dn2 = -8.0f * d2;
            }
#pragma unroll
            for (int r = 0; r < 11; ++r) {
                float cLo = ccur[4 + 2 * r], cHi = ccur[3 + 2 * r];
                float dLo = (cnxt[4 + 2 * r] - cLo) * inv_p;
                float dHi = (cnxt[3 + 2 * r] - cHi) * inv_p;
                cp[r].x = -fmaf(dLo, 3.5f, cLo);
                cp[r].y = -fmaf(dHi, 3.5f, cHi);
                d8[r].x = -8.0f * dLo;
                d8[r].y = -8.0f * dHi;
            }
            // prefetch frame f+2's coefficient row (hidden under 2 iterations)
            if (it < 4) {
                const int n2c = (nb + (it >> 1) + 2 < N_FRAMES) ? nb + (it >> 1) + 2 : N_FRAMES - 1;
                const float* r2 = arow + n2c * D_COEF;
#pragma unroll
                for (int q = 0; q < D_COEF; ++q) cfut[q] = r2[q];
            }
        }

#pragma unroll
        for (int gi = 0; gi < 5; ++gi) {
            const int tg = t0 + it * 40 + gi * 8;     // runtime (it), uniform shape

#pragma unroll
            for (int j = 0; j < 8; ++j) {
                const int P = 24 + gi * 8 + j;        // compile-time ring pos (mod-40 pattern)
                float xv = (j == 0) ? xb0[gi].x : (j == 1) ? xb0[gi].y
                         : (j == 2) ? xb0[gi].z : (j == 3) ? xb0[gi].w
                         : (j == 4) ? xb1[gi].x : (j == 5) ? xb1[gi].y
                         : (j == 6) ? xb1[gi].z : xb1[gi].w;
                float e = k * xv;

                // taps 3..24: 11 pk ops, 3 chains; pair r covers lags 3+2r,4+2r
                v2f A, B, C;
#pragma unroll
                for (int r = 0; r < 11; ++r) {
                    v2f pr = (P & 1) ? wB[slotBx(P - 3 - 2 * r)]
                                     : wA[slotA(P - 4 - 2 * r)];
                    if (r == 0)          A = cp[r] * pr;
                    else if (r == 1)     B = cp[r] * pr;
                    else if (r == 2)     C = cp[r] * pr;
                    else if (r % 3 == 0) A += cp[r] * pr;
                    else if (r % 3 == 1) B += cp[r] * pr;
                    else                 C += cp[r] * pr;
                }
                v2f S = (A + B) + C;
                float t1 = e + (S.x + S.y);
                float ym1 = (P & 1) ? wA[slotA(P - 1)].x  : wA[slotAy(P - 1)].y;  // y[P-1]
                float ym2 = (P & 1) ? wA[slotAy(P - 2)].y : wA[slotA(P - 2)].x;   // y[P-2]
                float u = fmaf(nc2, ym2, t1);
                float y = fmaf(nc1, ym1, u);

                // mirror write into both rings
                if (P & 1) {
                    wA[slotAy(P)].y = y;
                    wB[slotBx(P)].x = y;
                } else {
                    wA[slotA(P)].x = y;
                    wB[slotBy(P)].y = y;
                }
                k += dk;
            }

            if ((unsigned)(tg - s0) < 40u) {          // tg, s0 multiples of 8
                const int Q = 24 + gi * 8;            // even -> pairs from wA
                *(float4*)(orow + tg)     = make_float4(wA[slotA(Q + 0)].x, wA[slotA(Q + 0)].y,
                                                        wA[slotA(Q + 2)].x, wA[slotA(Q + 2)].y);
                *(float4*)(orow + tg + 4) = make_float4(wA[slotA(Q + 4)].x, wA[slotA(Q + 4)].y,
                                                        wA[slotA(Q + 6)].x, wA[slotA(Q + 6)].y);
            }

            // refill slot gi for iteration it+1 (distance = 5 groups ~1900
            // issue-cyc > HBM ~900 cyc). Consumed loads never clamp
            // (tg <= 63992); it=5 refills would be dead -> skipped.
            if (it < 5) {
                int tp = tg + 40; if (tp > T_SAMP - 8) tp = T_SAMP - 8;
                xb0[gi] = *(const float4*)(xrow + tp);
                xb1[gi] = *(const float4*)(xrow + tp + 4);
            }

            // per-group advance (last advance of a frame is dead: frame
            // setup recomputes before next consumption -> bit-identical)
            nc1 += dn1; nc2 += dn2;
#pragma unroll
            for (int r = 0; r < 11; ++r) cp[r] += d8[r];   // v_pk_add_f32
        }

        // rotate coefficient buffers at frame end (register movs)
        if ((it & 1) == 1 && it < 5) {
#pragma unroll
            for (int q = 0; q < D_COEF; ++q) { ccur[q] = cnxt[q]; cnxt[q] = cfut[q]; }
        }
    }
}

extern "C" void kernel_launch(void* const* d_in, const int* in_sizes, int n_in,
                              void* d_out, int out_size, void* d_ws, size_t ws_size,
                              hipStream_t stream) {
    const float* x = (const float*)d_in[0];
    const float* a = (const float*)d_in[1];
    float* out = (float*)d_out;

    dim3 block(64);
    dim3 grid(BATCH * CHUNKS / 64);      // 800 one-wave blocks
    hipLaunchKernelGGL(lpc_kernel, grid, block, 0, stream, x, a, out);
}

// Round 8
// 79.083 us; speedup vs baseline: 2.3251x; 1.0070x over previous
//
#include <hip/hip_runtime.h>

// AllPoleDigitalFilter via overlap-and-discard.
// R21: COALESCED LDS STAGING. R19 (x8 repeat) measured cold rep ~40us,
// warm ~15us; R20 (distance-5 prefetch) changed nothing => not latency
// depth. The closing arithmetic: every per-lane load is 64-way divergent
// (lanes 160B apart) => ~150 load instrs x 64 lines x 64B = ~0.5MB of
// line traffic PER WAVE (~400MB aggregate for a 13MB problem, 30-40x
// amplification). Warm reps = L2-resident (~15us), cold = L3 (~40us).
// Stores likewise 8x amplified. Matches every prior observation.
// Fix (keeping 800 one-wave blocks and the R20 register pipeline intact):
//  - Block stages its UNION x-window (2768 floats, 5.6x lane overlap) and
//    36 coeff rows into LDS with coalesced loads (~26 instrs, every byte
//    used). Inner xb refills become ds_read_b128 at distance-5 (latency
//    hidden; zero L2 traffic).
//  - Outputs staged per-lane in LDS (44-pad), one coalesced block store.
// Consumed values bit-identical to R18/R20 => absmax 0.03515625.
// R17 failed executing this idea by halving waves + serializing + scalar
// LDS reads in the loop; R21 keeps grid/occupancy/pipeline identical.

typedef float v2f __attribute__((ext_vector_type(2)));

#define BATCH 32
#define N_FRAMES 800
#define D_COEF 25
#define P_FRAME 80
#define T_SAMP 64000
#define LCH 40
#define CHUNKS 1600              // per batch row
#define BPR 25                   // blocks per batch row (1600/64)
#define XSZ 2768                 // union x-window: 31*80 + 240 + 48
#define CROWS 36                 // coeff rows staged: [nbase-1, nbase+34]
#define OPAD 44                  // output LDS row pad (16B-aligned rows)

// ring slot helpers (all args non-negative; +80 bias removes any doubt)
__device__ __forceinline__ constexpr int slotA(int s)  { return ((s + 80) % 40) / 2; }       // even s: wA[slotA].x=y[s]; odd s uses slotAy
__device__ __forceinline__ constexpr int slotAy(int s) { return ((s + 80 - 1) % 40) / 2; }   // odd s: wA[slotAy].y=y[s]
__device__ __forceinline__ constexpr int slotBx(int s) { return ((s + 80 - 1) % 40) / 2; }   // odd s: wB[slotBx].x=y[s]
__device__ __forceinline__ constexpr int slotBy(int s) { return ((s + 80 - 2) % 40) / 2; }   // even s: wB[slotBy].y=y[s]

__device__ __forceinline__ float4 lds4(const float* p) {
    return make_float4(p[0], p[1], p[2], p[3]);
}

__global__
__attribute__((amdgpu_flat_work_group_size(64, 64)))
__attribute__((amdgpu_waves_per_eu(1, 1)))
void lpc_kernel(const float* __restrict__ x,
                const float* __restrict__ a,
                float* __restrict__ out) {
    __shared__ float xs[XSZ];
    __shared__ float cs[CROWS * D_COEF];     // 900 floats
    __shared__ float outs[64 * OPAD];        // 2816 floats

    const int tid = threadIdx.x;
    const int c0 = blockIdx.x * 64;          // chunk base within batch row
    const int b  = blockIdx.y;
    const float* xrow = x + (size_t)b * T_SAMP;
    float* orow = out + (size_t)b * T_SAMP;
    const float* arow = a + (size_t)b * (N_FRAMES * D_COEF);

    const int nbase = (c0 >= 4) ? ((c0 - 4) >> 1) : 0;
    const int row0c = (nbase > 0) ? nbase - 1 : 0;
    const int xbase = (nbase * P_FRAME >= 48) ? nbase * P_FRAME - 48 : 0;
    // invariant: xbase + XSZ <= 64000 for all blocks (max block hits exactly).

    // ---- coalesced staging: load phase (all loads in flight), then write ----
    float4 st[11];                           // XSZ/4 = 692 = 10*64 + 52
#pragma unroll
    for (int q = 0; q < 11; ++q) {
        int fi = 4 * (tid + q * 64);
        if (fi < XSZ) st[q] = *(const float4*)(xrow + xbase + fi);
    }
    float cst[15];                           // 900 = 14*64 + 4
#pragma unroll
    for (int q = 0; q < 15; ++q) {
        int i = tid + q * 64;
        if (i < CROWS * D_COEF) {
            int r = i / D_COEF;
            int qq = i - r * D_COEF;
            int gr = row0c + r; if (gr > N_FRAMES - 1) gr = N_FRAMES - 1;
            cst[q] = arow[gr * D_COEF + qq];
        }
    }
#pragma unroll
    for (int q = 0; q < 11; ++q) {
        int fi = 4 * (tid + q * 64);
        if (fi < XSZ) {
            float* d = xs + fi;
            d[0] = st[q].x; d[1] = st[q].y; d[2] = st[q].z; d[3] = st[q].w;
        }
    }
#pragma unroll
    for (int q = 0; q < 15; ++q) {
        int i = tid + q * 64;
        if (i < CROWS * D_COEF) cs[i] = cst[q];
    }
    __syncthreads();

    // ---- per-lane setup ----
    const int ci = c0 + tid;
    const int s0 = ci * LCH;
    const int nb = (ci >= 4) ? ((ci - 4) >> 1) : 0;   // warm 160/200; ci<4 exact from t=0
    const int t0 = nb * P_FRAME;
    const int lx = t0 - xbase;               // lane's window base in xs (mult of 4)

    const float inv_p = 1.0f / (float)P_FRAME;

    v2f wA[20], wB[20];
#pragma unroll
    for (int i = 0; i < 20; ++i) {
        wA[i].x = 0.0f; wA[i].y = 0.0f;
        wB[i].x = 0.0f; wB[i].y = 0.0f;
    }

    // First-order refined warm-start (validated R15/R16), sources in LDS.
    if (nb > 0) {
        const float* rm1 = cs + (nb - 1 - row0c) * D_COEF;
        const float* cc0 = cs + (nb - row0c) * D_COEF;
        const float gm1 = rm1[0];
        const float dg = (cc0[0] - gm1) * inv_p;

        float z[48];
        const float* zr = xs + (lx - 48);
#pragma unroll
        for (int q = 0; q < 12; ++q) {
            float4 zq = lds4(zr + 4 * q);
            z[4 * q + 0] = zq.x; z[4 * q + 1] = zq.y;
            z[4 * q + 2] = zq.z; z[4 * q + 3] = zq.w;
        }
#pragma unroll
        for (int i = 0; i < 48; ++i) {
            float Kv = fmaf(dg, (float)(32 + i), gm1);
            z[i] *= Kv;
        }
        float am[24];
#pragma unroll
        for (int m = 0; m < 24; ++m) {
            float cc = rm1[1 + m];
            am[m] = fmaf(cc0[1 + m] - cc, 0.7f, cc);
        }
#pragma unroll
        for (int i = 0; i < 24; ++i) {
            float s = z[24 + i];
#pragma unroll
            for (int m = 1; m <= 24; ++m) s = fmaf(-am[m - 1], z[24 + i - m], s);
            if (i & 1) { wA[slotAy(i)].y = s; wB[slotBx(i)].x = s; }
            else       { wA[slotA(i)].x  = s; wB[slotBy(i)].y = s; }
        }
    }

    // x prefetch slots: xb[gi] holds group gi of the CURRENT 5-group block.
    float4 xb0[5], xb1[5];
#pragma unroll
    for (int gi = 0; gi < 5; ++gi) {
        xb0[gi] = lds4(xs + lx + gi * 8);
        xb1[gi] = lds4(xs + lx + gi * 8 + 4);
    }

    float k = 0.0f, dk = 0.0f, nc1 = 0.0f, nc2 = 0.0f, dn1 = 0.0f, dn2 = 0.0f;
    v2f cp[11], d8[11];
#pragma unroll
    for (int r = 0; r < 11; ++r) { cp[r].x = 0.0f; cp[r].y = 0.0f; d8[r].x = 0.0f; d8[r].y = 0.0f; }

    // 6 iterations x 5 groups = 30 groups = 3 frames (ring pattern period
    // is exactly 5 groups; frames advance 0 mod 40).
#pragma unroll 1
    for (int it = 0; it < 6; ++it) {
        if ((it & 1) == 0) {
            // frame setup from LDS coeff rows (uniform branch)
            const int f = it >> 1;
            int n1 = nb + f + 1; if (n1 > N_FRAMES - 1) n1 = N_FRAMES - 1;
            const float* r0 = cs + (nb + f - row0c) * D_COEF;
            const float* r1 = cs + (n1 - row0c) * D_COEF;

            float g0 = r0[0];
            dk = (r1[0] - g0) * inv_p;
            k = g0;
            {
                float c1 = r0[1], c2 = r0[2];
                float d1 = (r1[1] - c1) * inv_p;
                float d2 = (r1[2] - c2) * inv_p;
                nc1 = -fmaf(d1, 3.5f, c1);  dn1 = -8.0f * d1;
                nc2 = -fmaf(d2, 3.5f, c2);  dn2 = -8.0f * d2;
            }
#pragma unroll
            for (int r = 0; r < 11; ++r) {
                float cLo = r0[4 + 2 * r], cHi = r0[3 + 2 * r];
                float dLo = (r1[4 + 2 * r] - cLo) * inv_p;
                float dHi = (r1[3 + 2 * r] - cHi) * inv_p;
                cp[r].x = -fmaf(dLo, 3.5f, cLo);
                cp[r].y = -fmaf(dHi, 3.5f, cHi);
                d8[r].x = -8.0f * dLo;
                d8[r].y = -8.0f * dHi;
            }
        }

#pragma unroll
        for (int gi = 0; gi < 5; ++gi) {
            const int tg = t0 + it * 40 + gi * 8;     // runtime (it), uniform shape

#pragma unroll
            for (int j = 0; j < 8; ++j) {
                const int P = 24 + gi * 8 + j;        // compile-time ring pos (mod-40 pattern)
                float xv = (j == 0) ? xb0[gi].x : (j == 1) ? xb0[gi].y
                         : (j == 2) ? xb0[gi].z : (j == 3) ? xb0[gi].w
                         : (j == 4) ? xb1[gi].x : (j == 5) ? xb1[gi].y
                         : (j == 6) ? xb1[gi].z : xb1[gi].w;
                float e = k * xv;

                // taps 3..24: 11 pk ops, 3 chains; pair r covers lags 3+2r,4+2r
                v2f A, B, C;
#pragma unroll
                for (int r = 0; r < 11; ++r) {
                    v2f pr = (P & 1) ? wB[slotBx(P - 3 - 2 * r)]
                                     : wA[slotA(P - 4 - 2 * r)];
                    if (r == 0)          A = cp[r] * pr;
                    else if (r == 1)     B = cp[r] * pr;
                    else if (r == 2)     C = cp[r] * pr;
                    else if (r % 3 == 0) A += cp[r] * pr;
                    else if (r % 3 == 1) B += cp[r] * pr;
                    else                 C += cp[r] * pr;
                }
                v2f S = (A + B) + C;
                float t1 = e + (S.x + S.y);
                float ym1 = (P & 1) ? wA[slotA(P - 1)].x  : wA[slotAy(P - 1)].y;  // y[P-1]
                float ym2 = (P & 1) ? wA[slotAy(P - 2)].y : wA[slotA(P - 2)].x;   // y[P-2]
                float u = fmaf(nc2, ym2, t1);
                float y = fmaf(nc1, ym1, u);

                // mirror write into both rings
                if (P & 1) {
                    wA[slotAy(P)].y = y;
                    wB[slotBx(P)].x = y;
                } else {
                    wA[slotA(P)].x = y;
                    wB[slotBy(P)].y = y;
                }
                k += dk;
            }

            if ((unsigned)(tg - s0) < 40u) {          // output -> LDS row (pad 44)
                const int Q = 24 + gi * 8;            // even -> pairs from wA
                float* od = outs + tid * OPAD + (tg - s0);
                *(float4*)(od)     = make_float4(wA[slotA(Q + 0)].x, wA[slotA(Q + 0)].y,
                                                 wA[slotA(Q + 2)].x, wA[slotA(Q + 2)].y);
                *(float4*)(od + 4) = make_float4(wA[slotA(Q + 4)].x, wA[slotA(Q + 4)].y,
                                                 wA[slotA(Q + 6)].x, wA[slotA(Q + 6)].y);
            }

            // refill slot gi for iteration it+1 from LDS (distance 5 groups;
            // max offset lx+240 <= XSZ by construction; it=5 refills dead).
            if (it < 5) {
                const float* pp = xs + lx + it * 40 + gi * 8 + 40;
                xb0[gi] = lds4(pp);
                xb1[gi] = lds4(pp + 4);
            }

            // per-group advance (last advance of a frame is dead: frame
            // setup recomputes before next consumption -> bit-identical)
            nc1 += dn1; nc2 += dn2;
#pragma unroll
            for (int r = 0; r < 11; ++r) cp[r] += d8[r];   // v_pk_add_f32
        }
    }

    __syncthreads();

    // ---- coalesced block store: 64 chunks x 40 floats = 640 float4 ----
#pragma unroll
    for (int q = 0; q < 10; ++q) {
        int i = tid + q * 64;
        int fi = 4 * i;
        int r = fi / LCH;
        int c = fi - r * LCH;
        const float* sp = outs + r * OPAD + c;
        *(float4*)(orow + (size_t)c0 * LCH + fi) = make_float4(sp[0], sp[1], sp[2], sp[3]);
    }
}

extern "C" void kernel_launch(void* const* d_in, const int* in_sizes, int n_in,
                              void* d_out, int out_size, void* d_ws, size_t ws_size,
                              hipStream_t stream) {
    const float* x = (const float*)d_in[0];
    const float* a = (const float*)d_in[1];
    float* out = (float*)d_out;

    dim3 block(64);
    dim3 grid(BPR, BATCH);               // 25 x 32 = 800 one-wave blocks
    hipLaunchKernelGGL(lpc_kernel, grid, block, 0, stream, x, a, out);
}

// Round 9
// 72.431 us; speedup vs baseline: 2.5386x; 1.0918x over previous
//
#include <hip/hip_runtime.h>

// AllPoleDigitalFilter via overlap-and-discard.
// R22: WARM 80/120 + SECOND-ORDER WARM-START. Five refuted micro-theories
// (R15 TLP, R17/R21 divergence+coalescing, R18 I-cache, R20 latency depth)
// leave one surviving model: at <=1 wave/SIMD, kernel time = per-wave
// serial time ~ serial samples (R19: 240 samples -> 15.7us warm). Warm-up
// is 80% of serial work. Accuracy ledger: absmax bit-identical 0.03515625
// across W=320 zero-init / W=240 K-init (0.031 E0) / W=160 first-order
// (0.027 E0) => warm error invisible at 0.027 E0. Second-order init
// (y2 = z - A(z - Az), factor 0.053) at W=80: 0.053*rho^80 = 0.023 E0 --
// BELOW the proven-invisible level. Serial 240 -> 160 (2 frames/lane).
// Base = R16 (best, 75.7us): LCH=40, 800 one-wave blocks, waves_per_eu(1,1),
// coeff double-buffer ccur/cnxt/cfut, per-8-group midpoint taps, exact
// per-sample gain, dual-aligned v2f rings wA/wB (pk-FMA without
// pair-building movs), taps 1,2 scalar (1-FMA critical path), constexpr
// ring indices, dist-2 x prefetch.
//  - nb=(ci-2)>>1: warm 80 (even ci) / 120 (odd ci); ci<4 exact from t=0.
//  - frame loop f<2 (160 serial samples).
//  - warm-start: two Richardson passes over the 48-sample K*x window
//    (+576 FMA, ~0.5us), all indices compile-time.

typedef float v2f __attribute__((ext_vector_type(2)));

#define BATCH 32
#define N_FRAMES 800
#define D_COEF 25
#define P_FRAME 80
#define T_SAMP 64000
#define LCH 40
#define CHUNKS 1600              // per batch row

// ring slot helpers (all args non-negative; +80 bias removes any doubt)
__device__ __forceinline__ constexpr int slotA(int s)  { return ((s + 80) % 40) / 2; }       // even s: wA[slotA].x=y[s]; odd s uses slotAy
__device__ __forceinline__ constexpr int slotAy(int s) { return ((s + 80 - 1) % 40) / 2; }   // odd s: wA[slotAy].y=y[s]
__device__ __forceinline__ constexpr int slotBx(int s) { return ((s + 80 - 1) % 40) / 2; }   // odd s: wB[slotBx].x=y[s]
__device__ __forceinline__ constexpr int slotBy(int s) { return ((s + 80 - 2) % 40) / 2; }   // even s: wB[slotBy].y=y[s]

__global__
__attribute__((amdgpu_flat_work_group_size(64, 64)))
__attribute__((amdgpu_waves_per_eu(1, 1)))
void lpc_kernel(const float* __restrict__ x,
                const float* __restrict__ a,
                float* __restrict__ out) {
    const int g = blockIdx.x * 64 + threadIdx.x;
    const int b = g / CHUNKS;
    const int ci = g - b * CHUNKS;
    const int s0 = ci * LCH;
    const int nb = (ci >= 2) ? ((ci - 2) >> 1) : 0;   // warm 80 (even ci) / 120 (odd ci); ci<4 exact from t=0
    const int t0 = nb * P_FRAME;

    const float* xrow = x + (size_t)b * T_SAMP;
    float* orow = out + (size_t)b * T_SAMP;
    const float* arow = a + (size_t)b * (N_FRAMES * D_COEF);

    v2f wA[20], wB[20];
#pragma unroll
    for (int i = 0; i < 20; ++i) {
        wA[i].x = 0.0f; wA[i].y = 0.0f;
        wB[i].x = 0.0f; wB[i].y = 0.0f;
    }

    const float inv_p = 1.0f / (float)P_FRAME;

    // Coefficient register double-buffer: ccur = frame nb, cnxt = frame nb+1.
    float ccur[D_COEF], cnxt[D_COEF], cfut[D_COEF];
    {
        const float* rc = arow + nb * D_COEF;
        const int n1i = (nb + 1 < N_FRAMES) ? nb + 1 : N_FRAMES - 1;
        const float* rn = arow + n1i * D_COEF;
#pragma unroll
        for (int q = 0; q < D_COEF; ++q) { ccur[q] = rc[q]; cnxt[q] = rn[q]; }
    }

    // Second-order warm-start: ring positions P=0..23 hold y[t0-24..t0-1].
    // Samples t0-48+i sit at p=32+i of frame nb-1. z = K*x (exact gain
    // interp); taps am interpolated at history midpoint (frac 0.7).
    // Pass 1: y1 = z - A z;  Pass 2: y2 = z - A y1 (mixed y1/z lags,
    // all compile-time selects). Init error factor 0.053 vs 0.14 (1st) /
    // 0.38 (K-only) / 1.0 (zero).
    if (nb > 0) {
        const float* rm1 = arow + (nb - 1) * D_COEF;
        const float gm1 = rm1[0];
        const float dg = (ccur[0] - gm1) * inv_p;

        float z[48];
#pragma unroll
        for (int q = 0; q < 12; ++q) {
            float4 xq = *(const float4*)(xrow + t0 - 48 + 4 * q);
            z[4 * q + 0] = xq.x; z[4 * q + 1] = xq.y;
            z[4 * q + 2] = xq.z; z[4 * q + 3] = xq.w;
        }
#pragma unroll
        for (int i = 0; i < 48; ++i) {
            float Kv = fmaf(dg, (float)(32 + i), gm1);
            z[i] *= Kv;
        }
        float am[24];
#pragma unroll
        for (int m = 0; m < 24; ++m) {
            float c0 = rm1[1 + m];
            am[m] = fmaf(ccur[1 + m] - c0, 0.7f, c0);
        }
        float y1[24];
#pragma unroll
        for (int i = 0; i < 24; ++i) {
            float s = z[24 + i];
#pragma unroll
            for (int m = 1; m <= 24; ++m) s = fmaf(-am[m - 1], z[24 + i - m], s);
            y1[i] = s;
        }
#pragma unroll
        for (int i = 0; i < 24; ++i) {
            float s = z[24 + i];
#pragma unroll
            for (int m = 1; m <= 24; ++m) {
                float h = (i - m >= 0) ? y1[i - m] : z[24 + i - m];   // compile-time select
                s = fmaf(-am[m - 1], h, s);
            }
            if (i & 1) { wA[slotAy(i)].y = s; wB[slotBx(i)].x = s; }
            else       { wA[slotA(i)].x  = s; wB[slotBy(i)].y = s; }
        }
    }

    float4 xc0 = *(const float4*)(xrow + t0);
    float4 xc1 = *(const float4*)(xrow + t0 + 4);
    float4 xn0 = *(const float4*)(xrow + t0 + 8);
    float4 xn1 = *(const float4*)(xrow + t0 + 12);

#pragma unroll 1
    for (int f = 0; f < 2; ++f) {                 // 2 frames: warm<=120 + 40 out
        float g0 = ccur[0];
        float dk = (cnxt[0] - g0) * inv_p;
        float k = g0;

        float nc1, nc2, dn1, dn2;
        {
            float c1 = ccur[1], c2 = ccur[2];
            float d1 = (cnxt[1] - c1) * inv_p;
            float d2 = (cnxt[2] - c2) * inv_p;
            nc1 = -fmaf(d1, 3.5f, c1);  dn1 = -8.0f * d1;
            nc2 = -fmaf(d2, 3.5f, c2);  dn2 = -8.0f * d2;
        }
        v2f cp[11], d8[11];
#pragma unroll
        for (int r = 0; r < 11; ++r) {
            float cLo = ccur[4 + 2 * r], cHi = ccur[3 + 2 * r];
            float dLo = (cnxt[4 + 2 * r] - cLo) * inv_p;
            float dHi = (cnxt[3 + 2 * r] - cHi) * inv_p;
            cp[r].x = -fmaf(dLo, 3.5f, cLo);
            cp[r].y = -fmaf(dHi, 3.5f, cHi);
            d8[r].x = -8.0f * dLo;
            d8[r].y = -8.0f * dHi;
        }

        // Prefetch frame nb+2's coefficient row during f=0 (hidden under
        // one frame of compute; consumed at the f=0 -> f=1 rotation).
        if (f < 1) {
            const int n2 = (nb + 2 < N_FRAMES) ? nb + 2 : N_FRAMES - 1;
            const float* r2 = arow + n2 * D_COEF;
#pragma unroll
            for (int q = 0; q < D_COEF; ++q) cfut[q] = r2[q];
        }

        const int tf = t0 + f * P_FRAME;

#pragma unroll
        for (int gg = 0; gg < 10; ++gg) {
            const int tg = tf + gg * 8;
            int tp = tg + 16; if (tp > T_SAMP - 8) tp = T_SAMP - 8;
            float4 xf0 = *(const float4*)(xrow + tp);
            float4 xf1 = *(const float4*)(xrow + tp + 4);

#pragma unroll
            for (int j = 0; j < 8; ++j) {
                const int P = 24 + gg * 8 + j;        // compile-time ring pos
                float xv = (j == 0) ? xc0.x : (j == 1) ? xc0.y
                         : (j == 2) ? xc0.z : (j == 3) ? xc0.w
                         : (j == 4) ? xc1.x : (j == 5) ? xc1.y
                         : (j == 6) ? xc1.z : xc1.w;
                float e = k * xv;

                // taps 3..24: 11 pk ops, 3 chains; pair r covers lags 3+2r,4+2r
                v2f A, B, C;
#pragma unroll
                for (int r = 0; r < 11; ++r) {
                    // pair {y[P-4-2r], y[P-3-2r]}: even P from wA, odd P from wB
                    v2f pr = (P & 1) ? wB[slotBx(P - 3 - 2 * r)]
                                     : wA[slotA(P - 4 - 2 * r)];
                    if (r == 0)          A = cp[r] * pr;
                    else if (r == 1)     B = cp[r] * pr;
                    else if (r == 2)     C = cp[r] * pr;
                    else if (r % 3 == 0) A += cp[r] * pr;
                    else if (r % 3 == 1) B += cp[r] * pr;
                    else                 C += cp[r] * pr;
                }
                v2f S = (A + B) + C;
                float t1 = e + (S.x + S.y);
                float ym1 = (P & 1) ? wA[slotA(P - 1)].x  : wA[slotAy(P - 1)].y;  // y[P-1]
                float ym2 = (P & 1) ? wA[slotAy(P - 2)].y : wA[slotA(P - 2)].x;   // y[P-2]
                float u = fmaf(nc2, ym2, t1);
                float y = fmaf(nc1, ym1, u);

                // mirror write into both rings
                if (P & 1) {
                    wA[slotAy(P)].y = y;
                    wB[slotBx(P)].x = y;
                } else {
                    wA[slotA(P)].x = y;
                    wB[slotBy(P)].y = y;
                }
                k += dk;
            }

            if ((unsigned)(tg - s0) < 40u) {          // tg, s0 multiples of 8
                const int Q = 24 + gg * 8;            // Q even -> pairs from wA
                *(float4*)(orow + tg)     = make_float4(wA[slotA(Q + 0)].x, wA[slotA(Q + 0)].y,
                                                        wA[slotA(Q + 2)].x, wA[slotA(Q + 2)].y);
                *(float4*)(orow + tg + 4) = make_float4(wA[slotA(Q + 4)].x, wA[slotA(Q + 4)].y,
                                                        wA[slotA(Q + 6)].x, wA[slotA(Q + 6)].y);
            }
            if (gg < 9) {
                nc1 += dn1; nc2 += dn2;
#pragma unroll
                for (int r = 0; r < 11; ++r) cp[r] += d8[r];   // v_pk_add_f32
            }
            xc0 = xn0; xc1 = xn1;                     // rotate at group END
            xn0 = xf0; xn1 = xf1;
        }

        // Rotate coefficient buffers (register movs).
        if (f < 1) {
#pragma unroll
            for (int q = 0; q < D_COEF; ++q) { ccur[q] = cnxt[q]; cnxt[q] = cfut[q]; }
        }
    }
}

extern "C" void kernel_launch(void* const* d_in, const int* in_sizes, int n_in,
                              void* d_out, int out_size, void* d_ws, size_t ws_size,
                              hipStream_t stream) {
    const float* x = (const float*)d_in[0];
    const float* a = (const float*)d_in[1];
    float* out = (float*)d_out;

    dim3 block(64);
    dim3 grid(BATCH * CHUNKS / 64);      // 800 one-wave blocks
    hipLaunchKernelGGL(lpc_kernel, grid, block, 0, stream, x, a, out);
}

// Round 10
// 70.808 us; speedup vs baseline: 2.5968x; 1.0229x over previous
//
#include <hip/hip_runtime.h>

// AllPoleDigitalFilter via overlap-and-discard.
// R23: HALF-FRAME SEGMENTS, WARM 40, SERIAL 80. The only lever that has
// ever moved this kernel is serial sample count (R22: -80 samples ->
// -3.3us at ~41-62 ns/sample). Frame alignment forced warm>=80/120; this
// round aligns t0 to HALF-frames: t0 = 80m - 40 + 40*(ci&1), so every
// lane runs 2 segments x 40 samples (warm 40 + output 40, uniform across
// parities -- wave no longer gated by 120-warm odd lanes). Each segment
// has its own coeff setup at offset q in {0,40} (per-lane float, uniform
// code); ring slot pattern unchanged (40s = 0 mod 40, parity preserved).
// Accuracy ledger (absmax bit-identical 0.03515625 at init factors
// 0.0353/0.031/0.026/0.023 E0): warm 40 + THIRD-order init = 0.013 E0,
// below all proven-invisible levels. Even-lane z-window extends 8 samples
// into the prior frame: linear extrapolation of the (m-1,m) interp line;
// ci=2's t<0 region exactly zero-masked (true history IS zero).
// Segment-1 setup uses fmaf-at-offset-40 instead of accumulated advance
// -> last-bit rounding may differ from R22 (absmax ~0.0352, margin 3x).
// Base structure (validated R13..R22): dual-aligned v2f rings wA/wB
// (pk-FMA without pair-building movs), per-8-group midpoint taps, exact
// per-sample gain, taps 1,2 scalar, constexpr ring indices, dist-2 x
// prefetch, LCH=40, 800 one-wave blocks, waves_per_eu(1,1).

typedef float v2f __attribute__((ext_vector_type(2)));

#define BATCH 32
#define N_FRAMES 800
#define D_COEF 25
#define P_FRAME 80
#define T_SAMP 64000
#define LCH 40
#define CHUNKS 1600              // per batch row

// ring slot helpers (all args non-negative; +80 bias removes any doubt)
__device__ __forceinline__ constexpr int slotA(int s)  { return ((s + 80) % 40) / 2; }       // even s: wA[slotA].x=y[s]; odd s uses slotAy
__device__ __forceinline__ constexpr int slotAy(int s) { return ((s + 80 - 1) % 40) / 2; }   // odd s: wA[slotAy].y=y[s]
__device__ __forceinline__ constexpr int slotBx(int s) { return ((s + 80 - 1) % 40) / 2; }   // odd s: wB[slotBx].x=y[s]
__device__ __forceinline__ constexpr int slotBy(int s) { return ((s + 80 - 2) % 40) / 2; }   // even s: wB[slotBy].y=y[s]

__global__
__attribute__((amdgpu_flat_work_group_size(64, 64)))
__attribute__((amdgpu_waves_per_eu(1, 1)))
void lpc_kernel(const float* __restrict__ x,
                const float* __restrict__ a,
                float* __restrict__ out) {
    const int g = blockIdx.x * 64 + threadIdx.x;
    const int b = g / CHUNKS;
    const int ci = g - b * CHUNKS;
    const int s0 = ci * LCH;
    const int m  = ci >> 1;
    const int par = ci & 1;
    int t0 = P_FRAME * m - 40 + 40 * par;    // even: 80m-40, odd: 80m
    if (t0 < 0) t0 = 0;                      // ci in {0,1}: exact from t=0

    const float* xrow = x + (size_t)b * T_SAMP;
    float* orow = out + (size_t)b * T_SAMP;
    const float* arow = a + (size_t)b * (N_FRAMES * D_COEF);

    const float inv_p = 1.0f / (float)P_FRAME;

    // Coefficient rows m-1, m, m+1 (clamped). Union of needs:
    // z-init (A,B); seg0 even>=2 (A,B) / else (B,C); seg1 (B,C).
    const int rA = (m >= 1) ? m - 1 : 0;
    const int rC = (m + 1 < N_FRAMES) ? m + 1 : N_FRAMES - 1;
    float cA[D_COEF], cB[D_COEF], cC[D_COEF];
    {
        const float* pa = arow + rA * D_COEF;
        const float* pb = arow + m  * D_COEF;
        const float* pc = arow + rC * D_COEF;
#pragma unroll
        for (int q = 0; q < D_COEF; ++q) { cA[q] = pa[q]; cB[q] = pb[q]; cC[q] = pc[q]; }
    }

    v2f wA[20], wB[20];
#pragma unroll
    for (int i = 0; i < 20; ++i) {
        wA[i].x = 0.0f; wA[i].y = 0.0f;
        wB[i].x = 0.0f; wB[i].y = 0.0f;
    }

    // Third-order warm-start (3 Richardson passes): ring P=0..23 holds
    // y[t0-24..t0-1]. z = K*x over [t0-48, t0); position within frame m-1
    // is pz+i (pz = -8 even / 32 odd; extrapolated line for pz<0).
    // ci=2: zb=-8 -> t<0 elements exactly zeroed (true zero history).
    if (ci >= 2) {
        const int zb = t0 - 48;              // >= -8; negative only for ci==2
        float z[48];
#pragma unroll
        for (int q = 0; q < 12; ++q) {
            int ad = zb + 4 * q; if (ad < 0) ad = 0;
            float4 v = *(const float4*)(xrow + ad);
            z[4 * q + 0] = v.x; z[4 * q + 1] = v.y;
            z[4 * q + 2] = v.z; z[4 * q + 3] = v.w;
        }
#pragma unroll
        for (int i = 0; i < 8; ++i) z[i] = (zb + i >= 0) ? z[i] : 0.0f;

        const float pzf = (float)(t0 - P_FRAME * (m - 1) - 48);   // -8 or 32
        const float gm1 = cA[0];
        const float dg = (cB[0] - gm1) * inv_p;
#pragma unroll
        for (int i = 0; i < 48; ++i) {
            float Kv = fmaf(dg, pzf + (float)i, gm1);
            z[i] *= Kv;
        }
        const float frac = (pzf + 23.5f) * inv_p;   // z-window midpoint
        float am[24];
#pragma unroll
        for (int q = 0; q < 24; ++q) {
            float c0 = cA[1 + q];
            am[q] = fmaf(cB[1 + q] - c0, frac, c0);
        }
        float y1[24], y2[24];
#pragma unroll
        for (int i = 0; i < 24; ++i) {
            float s = z[24 + i];
#pragma unroll
            for (int q = 1; q <= 24; ++q) s = fmaf(-am[q - 1], z[24 + i - q], s);
            y1[i] = s;
        }
#pragma unroll
        for (int i = 0; i < 24; ++i) {
            float s = z[24 + i];
#pragma unroll
            for (int q = 1; q <= 24; ++q) {
                float h = (i - q >= 0) ? y1[i - q] : z[24 + i - q];   // compile-time select
                s = fmaf(-am[q - 1], h, s);
            }
            y2[i] = s;
        }
#pragma unroll
        for (int i = 0; i < 24; ++i) {
            float s = z[24 + i];
#pragma unroll
            for (int q = 1; q <= 24; ++q) {
                float h = (i - q >= 0) ? y2[i - q] : z[24 + i - q];
                s = fmaf(-am[q - 1], h, s);
            }
            if (i & 1) { wA[slotAy(i)].y = s; wB[slotBx(i)].x = s; }
            else       { wA[slotA(i)].x  = s; wB[slotBy(i)].y = s; }
        }
    }

    float4 xc0 = *(const float4*)(xrow + t0);
    float4 xc1 = *(const float4*)(xrow + t0 + 4);
    float4 xn0 = *(const float4*)(xrow + t0 + 8);
    float4 xn1 = *(const float4*)(xrow + t0 + 12);

    // Segment parameters. seg s covers samples t0+40s .. t0+40s+39 at
    // frame offset qf; seg0 rows: even>=2 -> (A,B) at q=40, else (B,C)
    // at q=0; seg1 rows: (B,C) at q = 40*par (ci<2: q=40).
    const bool segAB = (par == 0) && (ci >= 2);
    const float q0f = segAB ? 40.0f : 0.0f;
    const float q1f = (par || ci < 2) ? 40.0f : 0.0f;

    float k = 0.0f, dk = 0.0f, nc1 = 0.0f, nc2 = 0.0f, dn1 = 0.0f, dn2 = 0.0f;
    v2f cp[11], d8[11];

#pragma unroll
    for (int s = 0; s < 2; ++s) {
        const float qf = s ? q1f : q0f;
        auto LO = [&](int i) { return (s == 0) ? (segAB ? cA[i] : cB[i]) : cB[i]; };
        auto HI = [&](int i) { return (s == 0) ? (segAB ? cB[i] : cC[i]) : cC[i]; };

        // segment setup at offset qf (midpoint taps at qf+3.5, advance 8d/group)
        {
            float g0v = LO(0);
            dk = (HI(0) - g0v) * inv_p;
            k  = fmaf(dk, qf, g0v);
            float c1 = LO(1), c2 = LO(2);
            float d1 = (HI(1) - c1) * inv_p;
            float d2 = (HI(2) - c2) * inv_p;
            nc1 = -fmaf(d1, qf + 3.5f, c1);  dn1 = -8.0f * d1;
            nc2 = -fmaf(d2, qf + 3.5f, c2);  dn2 = -8.0f * d2;
#pragma unroll
            for (int r = 0; r < 11; ++r) {
                float cLo = LO(4 + 2 * r), cHi = LO(3 + 2 * r);
                float dLo = (HI(4 + 2 * r) - cLo) * inv_p;
                float dHi = (HI(3 + 2 * r) - cHi) * inv_p;
                cp[r].x = -fmaf(dLo, qf + 3.5f, cLo);
                cp[r].y = -fmaf(dHi, qf + 3.5f, cHi);
                d8[r].x = -8.0f * dLo;
                d8[r].y = -8.0f * dHi;
            }
        }

#pragma unroll
        for (int gi = 0; gi < 5; ++gi) {
            const int tg = t0 + 40 * s + 8 * gi;
            int tp = tg + 16; if (tp > T_SAMP - 8) tp = T_SAMP - 8;
            float4 xf0 = *(const float4*)(xrow + tp);
            float4 xf1 = *(const float4*)(xrow + tp + 4);

#pragma unroll
            for (int j = 0; j < 8; ++j) {
                const int P = 24 + gi * 8 + j;        // ring pos mod 40 (s adds 40 = 0 mod 40)
                float xv = (j == 0) ? xc0.x : (j == 1) ? xc0.y
                         : (j == 2) ? xc0.z : (j == 3) ? xc0.w
                         : (j == 4) ? xc1.x : (j == 5) ? xc1.y
                         : (j == 6) ? xc1.z : xc1.w;
                float e = k * xv;

                // taps 3..24: 11 pk ops, 3 chains; pair r covers lags 3+2r,4+2r
                v2f A, B, C;
#pragma unroll
                for (int r = 0; r < 11; ++r) {
                    v2f pr = (P & 1) ? wB[slotBx(P - 3 - 2 * r)]
                                     : wA[slotA(P - 4 - 2 * r)];
                    if (r == 0)          A = cp[r] * pr;
                    else if (r == 1)     B = cp[r] * pr;
                    else if (r == 2)     C = cp[r] * pr;
                    else if (r % 3 == 0) A += cp[r] * pr;
                    else if (r % 3 == 1) B += cp[r] * pr;
                    else                 C += cp[r] * pr;
                }
                v2f S = (A + B) + C;
                float t1 = e + (S.x + S.y);
                float ym1 = (P & 1) ? wA[slotA(P - 1)].x  : wA[slotAy(P - 1)].y;  // y[P-1]
                float ym2 = (P & 1) ? wA[slotAy(P - 2)].y : wA[slotA(P - 2)].x;   // y[P-2]
                float u = fmaf(nc2, ym2, t1);
                float y = fmaf(nc1, ym1, u);

                // mirror write into both rings
                if (P & 1) {
                    wA[slotAy(P)].y = y;
                    wB[slotBx(P)].x = y;
                } else {
                    wA[slotA(P)].x = y;
                    wB[slotBy(P)].y = y;
                }
                k += dk;
            }

            // store iff this group lies in [s0, s0+40): seg1 for all lanes
            // except ci=0, whose output is seg0 (tg,s0 multiples of 8).
            if ((unsigned)(tg - s0) < 40u) {
                const int Q = 24 + gi * 8;            // even -> pairs from wA
                *(float4*)(orow + tg)     = make_float4(wA[slotA(Q + 0)].x, wA[slotA(Q + 0)].y,
                                                        wA[slotA(Q + 2)].x, wA[slotA(Q + 2)].y);
                *(float4*)(orow + tg + 4) = make_float4(wA[slotA(Q + 4)].x, wA[slotA(Q + 4)].y,
                                                        wA[slotA(Q + 6)].x, wA[slotA(Q + 6)].y);
            }

            // per-group advance (last advance of a segment is dead: next
            // setup recomputes -> harmless)
            nc1 += dn1; nc2 += dn2;
#pragma unroll
            for (int r = 0; r < 11; ++r) cp[r] += d8[r];   // v_pk_add_f32
            xc0 = xn0; xc1 = xn1;                     // rotate at group END
            xn0 = xf0; xn1 = xf1;
        }
    }
}

extern "C" void kernel_launch(void* const* d_in, const int* in_sizes, int n_in,
                              void* d_out, int out_size, void* d_ws, size_t ws_size,
                              hipStream_t stream) {
    const float* x = (const float*)d_in[0];
    const float* a = (const float*)d_in[1];
    float* out = (float*)d_out;

    dim3 block(64);
    dim3 grid(BATCH * CHUNKS / 64);      // 800 one-wave blocks
    hipLaunchKernelGGL(lpc_kernel, grid, block, 0, stream, x, a, out);
}